// Round 11
// baseline (814.246 us; speedup 1.0000x reference)
//
#include <hip/hip_runtime.h>

#define N_NODES 45000
#define F_NNZ   33
#define NUM_STEPS 30
#define NWAVES  7500                 // 45000 / 6 rows per wave
#define HCHUNK  100
#define NHEADBLK (N_NODES / HCHUNK)  // 450

__device__ inline float bf2f(unsigned short u) {
    return __uint_as_float(((unsigned int)u) << 16);
}
__device__ inline unsigned short f2bf(float f) {
    unsigned int x = __float_as_uint(f);
    unsigned int r = (x + 0x7fffu + ((x >> 16) & 1u)) >> 16;   // RNE
    return (unsigned short)r;
}

// pk[t] = (bf16(values[t]) << 16) | u16(idx[t])   — 4 B per nnz entry
__global__ __launch_bounds__(256) void pack_kernel(const int* __restrict__ idx,
                                                   const float* __restrict__ values,
                                                   unsigned int* __restrict__ pk) {
    int t = blockIdx.x * 256 + threadIdx.x;
    if (t >= N_NODES * F_NNZ) return;
    unsigned int vb = f2bf(values[t]);
    pk[t] = (vb << 16) | (unsigned int)idx[t];
}

// x (B=64, N) -> xT (N,64) fp32 and g0 (N,64) = bf16(2x)  (h0 = x)
__global__ __launch_bounds__(256) void transpose_init(const float* __restrict__ x,
                                                      float* __restrict__ xT,
                                                      unsigned short* __restrict__ g0) {
    __shared__ float tile[64][65];
    int n0  = blockIdx.x * 64;
    int t   = threadIdx.x;
    int ln  = t & 63;
    int sub = t >> 6;
    for (int bb = 0; bb < 16; ++bb) {
        int b = bb * 4 + sub;
        int n = n0 + ln;
        float v = (n < N_NODES) ? x[(size_t)b * N_NODES + n] : 0.f;
        tile[ln][b] = v;
    }
    __syncthreads();
    for (int nn = 0; nn < 16; ++nn) {
        int nrel = nn * 4 + sub;
        int n = n0 + nrel;
        if (n < N_NODES) {
            float v = tile[nrel][ln];          // ln = b
            size_t pos = (size_t)n * 64 + ln;
            xT[pos] = v;
            g0[pos] = f2bf(2.f * v);
        }
    }
}

// Persistent step, full-width g (N,64) bf16 (one 128 B segment per gather).
// Depolluted L2: pk fetched per row with ONE nt vector load (lanes 0-32) into
// a wave-private LDS slot (no barrier; lgkmcnt-ordered), f-loop reads via LDS
// same-address broadcast. xT nt-load. gOut PLAIN store (allocates in L2 to
// seed next step's gathers). 1875 blocks x 4 waves = 7500 waves x exactly
// 6 rows — zero tail imbalance.
__global__ __launch_bounds__(256, 8) void step_kernel(const unsigned short* __restrict__ gIn,
                                                      const float* __restrict__ xT,
                                                      const unsigned int* __restrict__ pk,
                                                      const float* __restrict__ bias,
                                                      unsigned short* __restrict__ gOut,
                                                      int addX) {
    __shared__ unsigned int spk[4][33];
    int wid  = threadIdx.x >> 6;
    int lane = threadIdx.x & 63;     // b
    int w = (int)blockIdx.x * 4 + wid;        // 0..7499
#pragma unroll 1
    for (int it = 0; it < 6; ++it) {
        int n = w + it * NWAVES;
        // stage this row's 33 pk entries (nt: no K$/L2 pollution)
        if (lane < F_NNZ)
            spk[wid][lane] = __builtin_nontemporal_load(&pk[(size_t)n * F_NNZ + lane]);
        float acc = 0.f;
#pragma unroll
        for (int f = 0; f < F_NNZ; ++f) {
            unsigned int e = spk[wid][f];                  // LDS broadcast
            int   j = (int)(e & 0xffffu);
            float v = __uint_as_float(e & 0xffff0000u);    // bf16 value in hi bits
            acc = fmaf(v, bf2f(gIn[(size_t)j * 64 + lane]), acc);
        }
        float tv = fmaxf(acc + bias[n], 0.f);
        size_t o = (size_t)n * 64 + lane;
        float ov = tv;
        if (addX) ov += __builtin_nontemporal_load(&xT[o]);
        gOut[o] = f2bf(ov);                                // allocate in L2
    }
}

// Head GEMM partials. lane = b (coalesced 128 B h-row load), wave w owns
// h in [16w, 16w+16). Partial layout [h][b] (h*64 + b).
__global__ __launch_bounds__(256) void head_partial4(const unsigned short* __restrict__ h,
                                                     const float* __restrict__ w1,
                                                     float* __restrict__ partial) {
    int lane = threadIdx.x & 63;   // b
    int w    = threadIdx.x >> 6;   // h-group
    int n0   = blockIdx.x * HCHUNK;
    float acc[16];
#pragma unroll
    for (int k = 0; k < 16; ++k) acc[k] = 0.f;
    for (int i = 0; i < HCHUNK; ++i) {
        int n = n0 + i;
        float hv = bf2f(h[(size_t)n * 64 + lane]);           // coalesced
        const float* wrow = w1 + (size_t)n * 64 + w * 16;    // wave-uniform
#pragma unroll
        for (int k = 0; k < 16; ++k)
            acc[k] = fmaf(hv, wrow[k], acc[k]);
    }
    float* pp = partial + (size_t)blockIdx.x * 4096;
#pragma unroll
    for (int k = 0; k < 16; ++k)
        pp[(size_t)(w * 16 + k) * 64 + lane] = acc[k];       // [h][b]
}

// hidAcc[t] = sum over chunks of partial[chunk][t]  (layout [h][b] preserved)
__global__ __launch_bounds__(256) void head_reduce(const float* __restrict__ partial,
                                                   float* __restrict__ hidAcc) {
    int t = blockIdx.x * 256 + threadIdx.x;
    float acc = 0.f;
    for (int i = 0; i < NHEADBLK; ++i) acc += partial[(size_t)i * 4096 + t];
    hidAcc[t] = acc;
}

// out[b][c] = b2[c] + sum_h relu(hid[h][b] + b1[h]) * w2[h][c]   (hidAcc is [h][b])
__global__ __launch_bounds__(1024) void head_final(const float* __restrict__ hidAcc,
                                                   const float* __restrict__ b1,
                                                   const float* __restrict__ w2,
                                                   const float* __restrict__ b2,
                                                   float* __restrict__ out) {
    int t = threadIdx.x;
    if (t >= 640) return;
    int b = t / 10, c = t % 10;
    float acc = b2[c];
#pragma unroll
    for (int h = 0; h < 64; ++h) {
        float hv = fmaxf(hidAcc[h * 64 + b] + b1[h], 0.f);   // transposed read
        acc = fmaf(hv, w2[h * 10 + c], acc);
    }
    out[t] = acc;
}

extern "C" void kernel_launch(void* const* d_in, const int* in_sizes, int n_in,
                              void* d_out, int out_size, void* d_ws, size_t ws_size,
                              hipStream_t stream) {
    const float* x      = (const float*)d_in[0];
    const float* values = (const float*)d_in[1];
    const float* bias   = (const float*)d_in[2];
    const float* w1     = (const float*)d_in[3];
    const float* b1     = (const float*)d_in[4];
    const float* w2     = (const float*)d_in[5];
    const float* b2     = (const float*)d_in[6];
    const int*   idx    = (const int*)d_in[7];
    float* out = (float*)d_out;

    size_t per = (size_t)N_NODES * 64;
    float*          xT  = (float*)d_ws;                        // 11.5 MB
    unsigned short* gA  = (unsigned short*)(xT + per);         // 5.76 MB
    unsigned short* gB  = gA + per;                            // 5.76 MB
    unsigned int*   pk  = (unsigned int*)(gB + per);           // 5.94 MB
    float*          partial = (float*)(pk + (size_t)N_NODES * F_NNZ);  // 7.37 MB
    float*          hidAcc  = partial + (size_t)NHEADBLK * 4096;       // 16 KB

    pack_kernel<<<(N_NODES * F_NNZ + 255) / 256, 256, 0, stream>>>(idx, values, pk);
    transpose_init<<<(N_NODES + 63) / 64, 256, 0, stream>>>(x, xT, gA);

    const unsigned short* gin = gA;
    unsigned short*       gout = gB;
    for (int s = 0; s < NUM_STEPS; ++s) {
        int addX = (s < NUM_STEPS - 1) ? 1 : 0;
        step_kernel<<<1875, 256, 0, stream>>>(gin, xT, pk, bias, gout, addX);
        unsigned short* t0 = (unsigned short*)gin; gin = gout; gout = t0;
    }

    head_partial4<<<NHEADBLK, 256, 0, stream>>>(gin, w1, partial);
    head_reduce<<<16, 256, 0, stream>>>(partial, hidAcc);
    head_final<<<1, 1024, 0, stream>>>(hidAcc, b1, w2, b2, out);
}